// Round 1
// baseline (198.301 us; speedup 1.0000x reference)
//
#include <hip/hip_runtime.h>

// RoIAlign / crop-and-resize, TF2 half-pixel-center bilinear, POOL=7.
// fm: (256,256,512) fp32 NHWC; proposals: (N,4) int32 [x,y,w,h]; out: (N,7,7,512) fp32.

constexpr int FW = 256;   // feature map width
constexpr int FC = 512;   // channels

__device__ __forceinline__ void axis_coords(int start, int size, int p,
                                            int& c0, int& c1, float& frac) {
    // s = (p+0.5)*size/7 - 0.5, clipped to [0, size-1]; size >= 1 guaranteed.
    float s = ((float)p + 0.5f) * ((float)size / 7.0f) - 0.5f;
    s = fminf(fmaxf(s, 0.0f), (float)(size - 1));
    int i0 = (int)s;                 // s >= 0, truncation == floor
    int i1 = min(i0 + 1, size - 1);
    frac = s - (float)i0;
    c0 = start + i0;
    c1 = start + i1;
}

__global__ __launch_bounds__(128) void roi_align_kernel(
        const float* __restrict__ fm,
        const int*   __restrict__ props,
        float*       __restrict__ out) {
    const int blk = blockIdx.x;               // n*49 + py*7 + px
    const int n   = blk / 49;
    const int rem = blk - n * 49;
    const int py  = rem / 7;
    const int px  = rem - py * 7;

    const int4 box = ((const int4*)props)[n]; // x, y, w, h
    int x0, x1, y0, y1;
    float fx, fy;
    axis_coords(box.x, box.z, px, x0, x1, fx);
    axis_coords(box.y, box.w, py, y0, y1, fy);

    const float gx = 1.0f - fx, gy = 1.0f - fy;

    const float4* __restrict__ p00 = (const float4*)(fm + ((size_t)y0 * FW + x0) * FC);
    const float4* __restrict__ p01 = (const float4*)(fm + ((size_t)y0 * FW + x1) * FC);
    const float4* __restrict__ p10 = (const float4*)(fm + ((size_t)y1 * FW + x0) * FC);
    const float4* __restrict__ p11 = (const float4*)(fm + ((size_t)y1 * FW + x1) * FC);
    float4* __restrict__ po        = (float4*)(out + (size_t)blk * FC);

    const int c = threadIdx.x;                // 0..127, 4 channels each (FC/4 = 128)
    const float4 v00 = p00[c];
    const float4 v01 = p01[c];
    const float4 v10 = p10[c];
    const float4 v11 = p11[c];

    float4 r;
    r.x = (v00.x * gx + v01.x * fx) * gy + (v10.x * gx + v11.x * fx) * fy;
    r.y = (v00.y * gx + v01.y * fx) * gy + (v10.y * gx + v11.y * fx) * fy;
    r.z = (v00.z * gx + v01.z * fx) * gy + (v10.z * gx + v11.z * fx) * fy;
    r.w = (v00.w * gx + v01.w * fx) * gy + (v10.w * gx + v11.w * fx) * fy;
    po[c] = r;
}

extern "C" void kernel_launch(void* const* d_in, const int* in_sizes, int n_in,
                              void* d_out, int out_size, void* d_ws, size_t ws_size,
                              hipStream_t stream) {
    const float* fm    = (const float*)d_in[0];
    const int*   props = (const int*)d_in[1];
    float*       out   = (float*)d_out;

    const int N = in_sizes[1] / 4;            // 512 proposals
    roi_align_kernel<<<N * 49, 128, 0, stream>>>(fm, props, out);
}

// Round 3
// 198.017 us; speedup vs baseline: 1.0014x; 1.0014x over previous
//
#include <hip/hip_runtime.h>

// RoIAlign / crop-and-resize, TF2 half-pixel-center bilinear, POOL=7.
// fm: (256,256,512) fp32 NHWC; proposals: (N,4) int32 [x,y,w,h]; out: (N,7,7,512) fp32.
//
// R2: one block per (n, py) row -> 7 px points per block, fully unrolled.
// 28 independent 1KB/wave loads in flight per wave (vs 4 in R0) to hide
// cold-HBM latency; nontemporal stores (native vector type this time) keep
// the streaming output from evicting fm out of L2/L3.

constexpr int FW = 256;   // feature map width
constexpr int FC = 512;   // channels
constexpr int FC4 = FC / 4;

typedef float vfloat4 __attribute__((ext_vector_type(4)));  // native vector for builtins

__device__ __forceinline__ void axis_coords(int start, int size, int p,
                                            int& c0, int& c1, float& frac) {
    // s = (p+0.5)*size/7 - 0.5, clipped to [0, size-1]; size >= 1 guaranteed.
    float s = ((float)p + 0.5f) * ((float)size / 7.0f) - 0.5f;
    s = fminf(fmaxf(s, 0.0f), (float)(size - 1));
    int i0 = (int)s;                 // s >= 0, truncation == floor
    int i1 = min(i0 + 1, size - 1);
    frac = s - (float)i0;
    c0 = start + i0;
    c1 = start + i1;
}

__global__ __launch_bounds__(128) void roi_align_row_kernel(
        const float* __restrict__ fm,
        const int*   __restrict__ props,
        float*       __restrict__ out) {
    const int blk = blockIdx.x;               // n*7 + py
    const int n   = blk / 7;
    const int py  = blk - n * 7;

    const int4 box = ((const int4*)props)[n]; // x, y, w, h

    int y0, y1;
    float fy;
    axis_coords(box.y, box.w, py, y0, y1, fy);
    const float gy = 1.0f - fy;

    int   x0[7], x1[7];
    float fx[7];
#pragma unroll
    for (int px = 0; px < 7; ++px)
        axis_coords(box.x, box.z, px, x0[px], x1[px], fx[px]);

    const vfloat4* __restrict__ r0 = (const vfloat4*)(fm + (size_t)y0 * FW * FC);
    const vfloat4* __restrict__ r1 = (const vfloat4*)(fm + (size_t)y1 * FW * FC);
    vfloat4* __restrict__ po = (vfloat4*)(out + ((size_t)n * 49 + (size_t)py * 7) * FC);

    const int c = threadIdx.x;                // 0..127 -> float4 lane (FC4 = 128)

    // Issue all 28 loads up front (independent -> max memory-level parallelism).
    vfloat4 v00[7], v01[7], v10[7], v11[7];
#pragma unroll
    for (int px = 0; px < 7; ++px) {
        v00[px] = r0[x0[px] * FC4 + c];
        v01[px] = r0[x1[px] * FC4 + c];
        v10[px] = r1[x0[px] * FC4 + c];
        v11[px] = r1[x1[px] * FC4 + c];
    }

#pragma unroll
    for (int px = 0; px < 7; ++px) {
        const float fxp = fx[px], gxp = 1.0f - fx[px];
        vfloat4 top = v00[px] * gxp + v01[px] * fxp;
        vfloat4 bot = v10[px] * gxp + v11[px] * fxp;
        vfloat4 r   = top * gy + bot * fy;
        __builtin_nontemporal_store(r, &po[px * FC4 + c]);
    }
}

extern "C" void kernel_launch(void* const* d_in, const int* in_sizes, int n_in,
                              void* d_out, int out_size, void* d_ws, size_t ws_size,
                              hipStream_t stream) {
    const float* fm    = (const float*)d_in[0];
    const int*   props = (const int*)d_in[1];
    float*       out   = (float*)d_out;

    const int N = in_sizes[1] / 4;            // 512 proposals
    roi_align_row_kernel<<<N * 7, 128, 0, stream>>>(fm, props, out);
}